// Round 6
// baseline (312.156 us; speedup 1.0000x reference)
//
#include <hip/hip_runtime.h>
#include <cfloat>
#include <cstddef>

// VQ-VAE vector quantizer, MI355X / gfx950.
// z: (32, 64, 32, 32) f32 BCHW; embedding: (1024, 64) f32.
// Outputs concatenated f32: loss[1], z_q(BCHW)[2097152], perplexity[1],
// min_encodings[32768*1024], min_encoding_indices(as float)[32768].
//
// Structure history (measured):
//   R1 (108us): rows/lane, codes s_load-streamed -> SQC thrash, VALU 37%.
//   R2 (284us): codes via uniform-addr vector loads -> 64x RF replication.
//   R3 (154us): codes/lane C=2x8waves... 16 waves re-read every row from LDS
//     -> LDS return-bw bound (~8.8 cyc per broadcast b128, back-solved).
//   R4 (181us): rows scalar-streamed from BCHW (4KB stride) -> SMEM storm.
//   R5 (137us): channel-sliced codes + DPP/u64-swizzle reduce -> reduction
//     machinery ~2.3x inst bloat, 49% VALU with 50% dep bubbles.
//   R6 (this): C=4 codes/lane, 4 waves = full codebook -> each row broadcast
//     to only 4 waves (64 b128/row total, LDS-pipe-bound ~30-40us scan);
//     per-lane COMPLETE dots (lean R1-style argmin: in-lane tree + fmin
//     butterfly + ballot), no cross-lane dot reduce, no u64 keys.
//
// Numerics (must match the absmax-0.0 lineage bit-for-bit):
//   dot: per code, 4 fp32 fma chains m=c%4 over k ascending, final
//        (a0+a1)+(a2+a3); v_pk_fma_f32 pairs two CODES (independent chains)
//        -- proven exact R2-R5.
//   e2/z2: sequential double accumulation (ch ascending), rounded once.
//   d = (z2f + e2f) - 2.0f*dot (two fp32 roundings; 2x is exact so fma
//        contraction of the subtract is bit-identical).
//   argmin: j = 256q + 4*lane + c strictly monotone in (q, lane, c).
//     In-lane strict-< tree over c ascending; cross-lane fmin butterfly
//     (values only; fmin is symmetric) + ballot lowest lane; waves combined
//     ascending with strict < -> exact np.argmin first-index tie-break.
//   loss: partial[512] tree re-mapped to 4 waves x 4 passes with IDENTICAL
//     (group g, class) 8-term fma chains, identical shfl_down butterfly,
//     identical ascending-class sums -> bit-identical to R1/R4/R5.

#define NROWS 32768
#define NE    1024
#define EDIM  64
#define RPB   128
#define NBLK  (NROWS / RPB)   // 256 blocks = 1 per CU
#define TPB   256             // 4 waves; lane owns codes j = 256q + 4*lane + c
#define NPART 512

#define OFF_LOSS ((size_t)0)
#define OFF_ZQ   ((size_t)1)
#define OFF_PERP ((size_t)2097153)
#define OFF_OH   ((size_t)2097154)
#define OFF_IDX  ((size_t)35651586)

typedef float v2f __attribute__((ext_vector_type(2)));

// quad-lane fmin via DPP (0xB1 = quad_perm[1,0,3,2] -> xor1;
// 0x4E = quad_perm[2,3,0,1] -> xor2). update_dpp semantics proven in R5.
#define QMIN(X, PAT) do {                                                       \
    int _q = __builtin_amdgcn_update_dpp(0, __float_as_int(X), PAT, 0xF, 0xF, true); \
    X = fminf(X, __int_as_float(_q)); } while (0)

// ws layout (bytes): [0,4096) int hist[1024]; [4096,6144) float partial[512]

__global__ __launch_bounds__(TPB, 1) void vq_main(const float* __restrict__ z,
                                                  const float* __restrict__ emb,
                                                  int* __restrict__ hist,
                                                  float* __restrict__ partial,
                                                  float* __restrict__ out) {
    const int t    = threadIdx.x;
    const int lane = t & 63;
    const int q    = t >> 6;          // wave id 0..3; codes [256q, 256q+256)
    const int r0   = blockIdx.x * RPB;
    const int b    = r0 >> 10;        // 128 | 1024 -> single batch per block
    const int m0   = r0 & 1023;
    const size_t zb0 = (size_t)b * 65536 + (size_t)m0;

    __shared__ float zs[RPB][68];     // row-major z tile (S=68: b128-aligned)
    __shared__ float s_z2[RPB];
    __shared__ float s_wd[4][RPB];
    __shared__ int   s_wj[4][RPB];
    __shared__ int   s_idx[RPB];
    __shared__ float s_l2[2][8];

    // ---- stage 128 z-rows into LDS row-major ------------------------------
    // item i: r = i&127, qc = i>>7 (ch quad). 4 coalesced strided loads,
    // one float4 row-chunk ds_write (b128 writes = LDS BW floor, no
    // pathological conflict -- R5's column-scatter 32-way is gone).
#pragma unroll
    for (int it = 0; it < 8; ++it) {
        int i  = t + it * TPB;        // 0..2047
        int r  = i & 127;
        int qc = i >> 7;              // 0..15
        const float* zp = z + zb0 + (size_t)(4 * qc) * 1024 + r;
        float4 v;
        v.x = zp[0];
        v.y = zp[1024];
        v.z = zp[2048];
        v.w = zp[3072];
        *(float4*)&zs[r][4 * qc] = v;
    }

    // ---- ||z_r||^2 (verbatim sequential double chain, one rounding) -------
    if (t < RPB) {
        const float* zr = z + zb0 + t;
        double sd = 0.0;
#pragma unroll
        for (int c = 0; c < EDIM; ++c) {
            float v = zr[(size_t)c << 10];
            sd += (double)v * (double)v;
        }
        s_z2[t] = (float)sd;
    }

    // ---- resident codebook: 4 codes/lane as 2 code-pair v2f chain sets ----
    const int jb = (q << 8) + (lane << 2);
    v2f e01[16][4], e23[16][4];       // [k][m]: {e_j0[4k+m], e_j1[4k+m]} etc.
    float e2r0, e2r1, e2r2, e2r3;
    {
        const float4* p0 = (const float4*)(emb + ((size_t)(jb + 0) << 6));
        const float4* p1 = (const float4*)(emb + ((size_t)(jb + 1) << 6));
        const float4* p2 = (const float4*)(emb + ((size_t)(jb + 2) << 6));
        const float4* p3 = (const float4*)(emb + ((size_t)(jb + 3) << 6));
        double s0 = 0.0, s1 = 0.0, s2 = 0.0, s3 = 0.0;
#pragma unroll
        for (int k = 0; k < 16; ++k) {
            float4 v0 = p0[k], v1 = p1[k], v2 = p2[k], v3 = p3[k];
            e01[k][0] = (v2f){v0.x, v1.x};
            e01[k][1] = (v2f){v0.y, v1.y};
            e01[k][2] = (v2f){v0.z, v1.z};
            e01[k][3] = (v2f){v0.w, v1.w};
            e23[k][0] = (v2f){v2.x, v3.x};
            e23[k][1] = (v2f){v2.y, v3.y};
            e23[k][2] = (v2f){v2.z, v3.z};
            e23[k][3] = (v2f){v2.w, v3.w};
            s0 += (double)v0.x * v0.x; s0 += (double)v0.y * v0.y;
            s0 += (double)v0.z * v0.z; s0 += (double)v0.w * v0.w;
            s1 += (double)v1.x * v1.x; s1 += (double)v1.y * v1.y;
            s1 += (double)v1.z * v1.z; s1 += (double)v1.w * v1.w;
            s2 += (double)v2.x * v2.x; s2 += (double)v2.y * v2.y;
            s2 += (double)v2.z * v2.z; s2 += (double)v2.w * v2.w;
            s3 += (double)v3.x * v3.x; s3 += (double)v3.y * v3.y;
            s3 += (double)v3.z * v3.z; s3 += (double)v3.w * v3.w;
        }
        e2r0 = (float)s0; e2r1 = (float)s1; e2r2 = (float)s2; e2r3 = (float)s3;
    }

    // drain ALL loads before issuing zero-fill stores, so no later load-wait
    // ever has the (slow-draining) stores older in its vmcnt count
    asm volatile("s_waitcnt vmcnt(0)" ::: "memory");

    // ---- fire-and-forget zero-fill of this block's one-hot slab ----------
    // 128 rows x 4KB contiguous; the scan is LDS/VALU only and the barrier
    // below waits lgkm only -> stores drain under ~35us of scan; the
    // post-scan __syncthreads (vmcnt 0) orders the 1.0f scatter after them.
    {
        float* ohb = out + OFF_OH + (size_t)r0 * 1024;   // 131072 floats
        if (t == 0) {
            *(float2*)ohb              = make_float2(0.f, 0.f);
            *(float2*)(ohb + 131070)   = make_float2(0.f, 0.f);
        }
        float4* p4 = (float4*)(ohb + 2);                 // 16B-aligned
        const float4 z4 = make_float4(0.f, 0.f, 0.f, 0.f);
        for (int i = t; i < 32767; i += TPB) p4[i] = z4;
    }

    // raw barrier: LDS producers flushed; vmem stores stay in flight
    asm volatile("s_waitcnt lgkmcnt(0)" ::: "memory");
    __builtin_amdgcn_s_barrier();

    // ---- scan: 128 rows; each wave covers its 256 codes -------------------
    for (int r = 0; r < RPB; ++r) {
        float4 zz[16];
#pragma unroll
        for (int k = 0; k < 16; ++k) zz[k] = *(const float4*)&zs[r][4 * k];
        float z2r = s_z2[r];

        v2f a01[4] = {{0.f,0.f},{0.f,0.f},{0.f,0.f},{0.f,0.f}};
        v2f a23[4] = {{0.f,0.f},{0.f,0.f},{0.f,0.f},{0.f,0.f}};
#pragma unroll
        for (int k = 0; k < 16; ++k) {
            float4 zv = zz[k];
            v2f zx = {zv.x, zv.x}, zy = {zv.y, zv.y};
            v2f zzw = {zv.z, zv.z}, zw = {zv.w, zv.w};
            a01[0] = __builtin_elementwise_fma(e01[k][0], zx,  a01[0]);
            a01[1] = __builtin_elementwise_fma(e01[k][1], zy,  a01[1]);
            a01[2] = __builtin_elementwise_fma(e01[k][2], zzw, a01[2]);
            a01[3] = __builtin_elementwise_fma(e01[k][3], zw,  a01[3]);
            a23[0] = __builtin_elementwise_fma(e23[k][0], zx,  a23[0]);
            a23[1] = __builtin_elementwise_fma(e23[k][1], zy,  a23[1]);
            a23[2] = __builtin_elementwise_fma(e23[k][2], zzw, a23[2]);
            a23[3] = __builtin_elementwise_fma(e23[k][3], zw,  a23[3]);
        }
        float dot0 = (a01[0].x + a01[1].x) + (a01[2].x + a01[3].x);
        float dot1 = (a01[0].y + a01[1].y) + (a01[2].y + a01[3].y);
        float dot2 = (a23[0].x + a23[1].x) + (a23[2].x + a23[3].x);
        float dot3 = (a23[0].y + a23[1].y) + (a23[2].y + a23[3].y);
        float d0 = (z2r + e2r0) - 2.0f * dot0;
        float d1 = (z2r + e2r1) - 2.0f * dot1;
        float d2 = (z2r + e2r2) - 2.0f * dot2;
        float d3 = (z2r + e2r3) - 2.0f * dot3;
        // in-lane strict-< tree, c ascending: first index on ties
        float eA = (d1 < d0) ? d1 : d0;  int cA = (d1 < d0) ? 1 : 0;
        float eB = (d3 < d2) ? d3 : d2;  int cB = (d3 < d2) ? 3 : 2;
        float dl = (eB < eA) ? eB : eA;  int cl = (eB < eA) ? cB : cA;
        // wave-wide min value: 2 DPP quad stages + 4 shfl_xor (symmetric)
        float mm = dl;
        QMIN(mm, 0xB1);                       // xor 1
        QMIN(mm, 0x4E);                       // xor 2
        mm = fminf(mm, __shfl_xor(mm, 4));
        mm = fminf(mm, __shfl_xor(mm, 8));
        mm = fminf(mm, __shfl_xor(mm, 16));
        mm = fminf(mm, __shfl_xor(mm, 32));
        // first-index winner: j monotone in (lane, c) -> lowest lane wins
        unsigned long long bal = __ballot(dl == mm);
        int wl = __ffsll((long long)bal) - 1;             // uniform
        int cw = __builtin_amdgcn_readlane(cl, wl);
        if (lane == 0) {
            s_wd[q][r] = mm;
            s_wj[q][r] = (q << 8) + (wl << 2) + cw;
        }
    }
    __syncthreads();   // full barrier: vmcnt(0) -> zero-fill globally visible

    // ---- combine 4 per-wave candidates per row (ascending code chunks) ----
    if (t < RPB) {
        float bd = s_wd[0][t];
        int   bj = s_wj[0][t];
#pragma unroll
        for (int w = 1; w < 4; ++w) {
            float dw = s_wd[w][t];
            if (dw < bd) { bd = dw; bj = s_wj[w][t]; }  // strict <: first index
        }
        s_idx[t] = bj;
        out[OFF_IDX + (size_t)(r0 + t)] = (float)bj;
        out[OFF_OH + (size_t)(r0 + t) * 1024 + bj] = 1.0f;
        atomicAdd(&hist[bj], 1);
    }
    __syncthreads();

    // ---- z_q (straight-through) + loss partials ---------------------------
    // 16 (group g, class) tasks; wave w pass p: g = w&1, class = (w>>1)+2p.
    // Chains / butterfly / ascending-class sums identical to R1/R4/R5 ->
    // partial[512] bit-identical; vq_final unchanged.
    {
        const int g    = q & 1;
        const int r    = (g << 6) + lane;
        const int grow = r0 + r;
        const int bb   = grow >> 10;
        const int mm2  = grow & 1023;
        const size_t zbr = (size_t)bb * 65536 + (size_t)mm2;
        const int    jjx = s_idx[r];
        const float* er  = emb + ((size_t)jjx << 6);
        float* zq = out + OFF_ZQ + zbr;
#pragma unroll
        for (int p = 0; p < 4; ++p) {
            const int cls = (q >> 1) + 2 * p;   // {0,2,4,6} or {1,3,5,7}
            float ls = 0.f;
#pragma unroll
            for (int i = 0; i < 8; ++i) {
                int c = cls + 8 * i;
                float zc   = z[zbr + (size_t)c * 1024];   // coalesced
                float ev   = er[c];                       // gather (L2-hot)
                float diff = ev - zc;
                zq[(size_t)c * 1024] = zc + diff;         // zp + (z_q - zp)
                ls = fmaf(diff, diff, ls);
            }
#pragma unroll
            for (int off = 32; off >= 1; off >>= 1) ls += __shfl_down(ls, off);
            if (lane == 0) s_l2[g][cls] = ls;
        }
        __syncthreads();
        if (t == 0) {
            float sA = 0.f, sB = 0.f;
#pragma unroll
            for (int c = 0; c < 8; ++c) {   // ascending class, as always
                sA += s_l2[0][c];
                sB += s_l2[1][c];
            }
            partial[2 * blockIdx.x + 0] = sA;
            partial[2 * blockIdx.x + 1] = sB;
        }
    }
}

__global__ __launch_bounds__(1024) void vq_final(const int* __restrict__ hist,
                                                 const float* __restrict__ partial,
                                                 float* __restrict__ out) {
    int t = threadIdx.x;
    float p    = (float)hist[t] * (1.0f / 32768.0f);
    float term = p * logf(p + 1e-10f);
    float lp   = (t < NPART) ? partial[t] : 0.f;
#pragma unroll
    for (int off = 32; off >= 1; off >>= 1) {
        term += __shfl_down(term, off);
        lp   += __shfl_down(lp, off);
    }
    __shared__ float st[16], sl[16];
    int w = t >> 6, ln = t & 63;
    if (ln == 0) { st[w] = term; sl[w] = lp; }
    __syncthreads();
    if (t == 0) {
        float s = 0.f, l = 0.f;
#pragma unroll
        for (int i = 0; i < 16; ++i) { s += st[i]; l += sl[i]; }
        out[OFF_LOSS] = 1.25f * l * (1.0f / 2097152.0f);  // (1+beta)*mean
        out[OFF_PERP] = expf(-s);
    }
}

extern "C" void kernel_launch(void* const* d_in, const int* in_sizes, int n_in,
                              void* d_out, int out_size, void* d_ws, size_t ws_size,
                              hipStream_t stream) {
    const float* z   = (const float*)d_in[0];
    const float* emb = (const float*)d_in[1];
    float* out     = (float*)d_out;
    int*   hist    = (int*)d_ws;
    float* partial = (float*)((char*)d_ws + 4096);

    hipMemsetAsync(hist, 0, 4096, stream);
    vq_main<<<NBLK, TPB, 0, stream>>>(z, emb, hist, partial, out);
    vq_final<<<1, 1024, 0, stream>>>(hist, partial, out);
}

// Round 7
// 226.369 us; speedup vs baseline: 1.3790x; 1.3790x over previous
//
#include <hip/hip_runtime.h>
#include <cfloat>
#include <cstddef>

// VQ-VAE vector quantizer, MI355X / gfx950.
// z: (32, 64, 32, 32) f32 BCHW; embedding: (1024, 64) f32.
// Outputs concatenated f32: loss[1], z_q(BCHW)[2097152], perplexity[1],
// min_encodings[32768*1024], min_encoding_indices(as float)[32768].
//
// Structure history (measured):
//   R1 (108us): rows/lane, codes s_load, 8 DISJOINT streams/block -> sL1
//     thrash + no SGPR dbuf headroom, VALU 37%.
//   R2 (284us): uniform-addr vector loads -> 64x RF replication.
//   R3 (154us): rows LDS-broadcast to 16 waves -> LDS return-bw bound.
//   R4 (181us): rows scalar-streamed at 4KB stride -> SMEM issue storm
//     (scalar path needs CONTIGUOUS streams).
//   R5 (137us): quad-sliced codes -> reduction machinery 2x inst bloat.
//   R6 (199us): 4 codes/lane resident -> RF overflow (AGPR shuffling) +
//     1 wave/SIMD = all latency exposed.
//   R7 (this): scan/epilogue split. Scan: grid 128 row-blocks x 4 code-
//     blocks, TPB 512, launch_bounds(512,4) -> 2 blocks/CU = 4 waves/SIMD
//     TLP. Lane owns a row (64f in VGPR); wave s_load-streams 128 codes
//     (contiguous 256B rows); only 4 streams/CU each shared by 4 waves
//     (re-synced by raw s_barrier every 32 codes) -> sL1-friendly. Per-lane
//     argmin only (no cross-lane reduce). Candidates stashed in the z_q
//     region (channels 0..15), consumed and overwritten by the epilogue.
//     One-hot zero-fill issued fire-and-forget before the scan (scan has
//     zero vmem waits; raw barriers wait nothing).
//
// Numerics (must match the absmax-0.0 lineage bit-for-bit):
//   dot: 4 fp32 fma chains m=c%4 over k ascending, final (a0+a1)+(a2+a3);
//     v_pk_fma_f32 packs chains (a0,a1),(a2,a3) -- identical per-element
//     rounding, proven exact R2-R6.
//   e2/z2: sequential double accumulation (ch ascending), rounded once
//     (e2 in a pre-kernel, proven R5; z2 from the row regs, c ascending).
//   d = (z2f + e2f) - 2.0f*dot (two fp32 roundings at magnitude ~64).
//   argmin: lane scans its 128 codes ascending with strict < (first index);
//     epilogue combines the 8 chunk-candidates in ascending-chunk order with
//     strict < -> exact np.argmin first-index tie-break.
//   loss: epilogue reproduces R1's partial[512] tree verbatim (64-row
//     groups, class chains c0+8i, shfl_down butterfly, ascending-class
//     sums); vq_final unchanged.

#define NROWS 32768
#define NE    1024
#define EDIM  64
#define TPB_A 512
#define GRID_A 512            // 128 row-blocks x 4 code-blocks
#define TPB_B 256
#define GRID_B 512            // 64 rows each
#define NPART 512

#define OFF_LOSS ((size_t)0)
#define OFF_ZQ   ((size_t)1)
#define OFF_PERP ((size_t)2097153)
#define OFF_OH   ((size_t)2097154)
#define OFF_IDX  ((size_t)35651586)

typedef float v2f __attribute__((ext_vector_type(2)));

// ws layout (bytes): [0,4096) int hist[1024]; [4096,6144) float partial[512];
//                    [8192,12288) float e2buf[1024]

__global__ __launch_bounds__(128) void vq_e2(const float* __restrict__ emb,
                                             float* __restrict__ e2buf) {
    int j = blockIdx.x * 128 + threadIdx.x;          // grid 8x128 = 1024
    const float* e = emb + ((size_t)j << 6);
    double s = 0.0;
#pragma unroll
    for (int c = 0; c < EDIM; ++c) { float v = e[c]; s += (double)v * (double)v; }
    e2buf[j] = (float)s;
}

__global__ __launch_bounds__(TPB_A, 4) void vq_scan(const float* __restrict__ z,
                                                    const float* __restrict__ emb,
                                                    const float* __restrict__ e2buf,
                                                    float* __restrict__ out) {
    const int t    = threadIdx.x;
    const int lane = t & 63;
    const int q    = t >> 6;                 // wave 0..7
    const int rb   = blockIdx.x >> 2;        // row-block 0..127
    const int cb   = blockIdx.x & 3;         // code-block 0..3
    const int r0   = rb << 8;                // 256 rows per block
    const int rg   = q & 3;                  // row group within block
    // hf selects the wave's 128-code half; readfirstlane makes it provably
    // wave-uniform so the codebook loads compile to s_load (R1-proven).
    const int hf   = __builtin_amdgcn_readfirstlane(q >> 2);

    const int row  = r0 + (rg << 6) + lane;
    const int b    = row >> 10;
    const int m    = row & 1023;
    const size_t zbase = (size_t)b * 65536 + (size_t)m;

    // ---- this lane's z row (64 ch, stride 1024) + ||z||^2 -----------------
    v2f zp[32];
    double sd = 0.0;
#pragma unroll
    for (int n = 0; n < 32; ++n) {
        float x = z[zbase + (size_t)(2 * n) * 1024];
        float y = z[zbase + (size_t)(2 * n + 1) * 1024];
        zp[n] = (v2f){x, y};
        sd += (double)x * (double)x;         // c ascending: 2n then 2n+1
        sd += (double)y * (double)y;
    }
    const float z2f = (float)sd;

    // ---- fire-and-forget zero-fill: this block's one-hot column chunk ----
    // rows [r0, r0+256) x cols [cb*256, +256) = 256 KB. float2 (8B-aligned;
    // OFF_OH is even). The scan below is SMEM/VALU only and its barriers
    // are raw s_barrier (no waitcnt) -> these stores drain under the scan.
    {
        float* basep = out + OFF_OH + (size_t)r0 * 1024 + (cb << 8);
        for (int i = t; i < 32768; i += TPB_A) {
            int r  = i >> 7;                 // 0..255
            int c2 = i & 127;                // float2 column
            *(float2*)(basep + (size_t)r * 1024 + 2 * c2) = make_float2(0.f, 0.f);
        }
    }

    // ---- scan this wave's 128 codes via shared scalar stream --------------
    // All 4 waves with the same (cb,hf) on a CU read the SAME contiguous
    // 32KB codebook chunk in the same order (one wave per SIMD); raw
    // barriers every 32 codes keep the streams tight in sL1.
    const int jf = (cb << 8) + (hf << 7);
    float bestd = FLT_MAX;
    int   bestj = 0;
    for (int jj = 0; jj < 128; ++jj) {
        const int j = jf + jj;
        const float4* ep = (const float4*)(emb + ((size_t)j << 6));
        const float e2f = e2buf[j];          // s_load (uniform)
        float4 e[16];
#pragma unroll
        for (int k = 0; k < 16; ++k) e[k] = ep[k];   // s_load_dwordx16 x4
        v2f a01 = {0.f, 0.f}, a23 = {0.f, 0.f};
#pragma unroll
        for (int k = 0; k < 16; ++k) {
            v2f exy = {e[k].x, e[k].y};
            v2f ezw = {e[k].z, e[k].w};
            a01 = __builtin_elementwise_fma(exy, zp[2 * k],     a01);
            a23 = __builtin_elementwise_fma(ezw, zp[2 * k + 1], a23);
        }
        float dot = (a01.x + a01.y) + (a23.x + a23.y);
        float d   = (z2f + e2f) - 2.0f * dot;
        if (d < bestd) { bestd = d; bestj = j; }     // ascending: first index
        if ((jj & 31) == 31) __builtin_amdgcn_s_barrier();  // raw: no waits
    }

    // ---- stash candidate (d, j) in the z_q region, channels 2gc, 2gc+1 ----
    // The epilogue kernel reads these for its rows BEFORE overwriting the
    // region with z_q (kernel boundary orders scan-writes vs epi-reads).
    const int gc = (cb << 1) + hf;           // global chunk 0..7, ascending j
    out[OFF_ZQ + zbase + (size_t)(2 * gc) * 1024]     = bestd;
    out[OFF_ZQ + zbase + (size_t)(2 * gc + 1) * 1024] = __int_as_float(bestj);
}

__global__ __launch_bounds__(TPB_B) void vq_epi(const float* __restrict__ z,
                                                const float* __restrict__ emb,
                                                int* __restrict__ hist,
                                                float* __restrict__ partial,
                                                float* __restrict__ out) {
    const int t    = threadIdx.x;
    const int lane = t & 63;
    const int q    = t >> 6;                 // wave 0..3
    const int r0   = blockIdx.x << 6;        // 64 rows per block

    __shared__ int   s_idx[64];
    __shared__ float s_l[8];

    // ---- combine 8 chunk candidates per row (ascending chunk = ascending
    //      code range; strict < keeps the first/lowest index) --------------
    if (t < 64) {
        const int row = r0 + t;
        const int b   = row >> 10;
        const int m   = row & 1023;
        const size_t zbase = (size_t)b * 65536 + (size_t)m;
        const float* cp = out + OFF_ZQ + zbase;
        float bd = cp[0];
        int   bj = __float_as_int(cp[1024]);
#pragma unroll
        for (int gc = 1; gc < 8; ++gc) {
            float d = cp[(size_t)(2 * gc) * 1024];
            int   j = __float_as_int(cp[(size_t)(2 * gc + 1) * 1024]);
            if (d < bd) { bd = d; bj = j; }
        }
        s_idx[t] = bj;
        out[OFF_IDX + row] = (float)bj;                       // index as float
        out[OFF_OH + (size_t)row * 1024 + bj] = 1.0f;         // one-hot scatter
        atomicAdd(&hist[bj], 1);
    }
    __syncthreads();   // candidates of ALL rows read before z_q overwrites

    // ---- z_q (straight-through) + loss partial: R1's tree verbatim -------
    // wave q handles classes {q, q+4}; chains c = cls + 8i (i ascending),
    // shfl_down butterfly, s_l[8] summed ascending -> partial[512]
    // bit-identical to the R1 lineage; vq_final unchanged.
    {
        const int row = r0 + lane;
        const int b   = row >> 10;
        const int m   = row & 1023;
        const size_t zbr = (size_t)b * 65536 + (size_t)m;
        const int    jjx = s_idx[lane];
        const float* er  = emb + ((size_t)jjx << 6);
        float* zq = out + OFF_ZQ + zbr;
#pragma unroll
        for (int p = 0; p < 2; ++p) {
            const int cls = q + 4 * p;
            float ls = 0.f;
#pragma unroll
            for (int i = 0; i < 8; ++i) {
                int c = cls + 8 * i;
                float zc   = z[zbr + (size_t)c * 1024];       // coalesced
                float ev   = er[c];                           // gather (L2)
                float diff = ev - zc;
                zq[(size_t)c * 1024] = zc + diff;             // zp + (z_q-zp)
                ls = fmaf(diff, diff, ls);
            }
#pragma unroll
            for (int off = 32; off >= 1; off >>= 1) ls += __shfl_down(ls, off);
            if (lane == 0) s_l[cls] = ls;
        }
        __syncthreads();
        if (t == 0) {
            float l = 0.f;
#pragma unroll
            for (int c = 0; c < 8; ++c) l += s_l[c];          // ascending
            partial[blockIdx.x] = l;
        }
    }
}

__global__ __launch_bounds__(1024) void vq_final(const int* __restrict__ hist,
                                                 const float* __restrict__ partial,
                                                 float* __restrict__ out) {
    int t = threadIdx.x;
    float p    = (float)hist[t] * (1.0f / 32768.0f);
    float term = p * logf(p + 1e-10f);
    float lp   = (t < NPART) ? partial[t] : 0.f;
#pragma unroll
    for (int off = 32; off >= 1; off >>= 1) {
        term += __shfl_down(term, off);
        lp   += __shfl_down(lp, off);
    }
    __shared__ float st[16], sl[16];
    int w = t >> 6, ln = t & 63;
    if (ln == 0) { st[w] = term; sl[w] = lp; }
    __syncthreads();
    if (t == 0) {
        float s = 0.f, l = 0.f;
#pragma unroll
        for (int i = 0; i < 16; ++i) { s += st[i]; l += sl[i]; }
        out[OFF_LOSS] = 1.25f * l * (1.0f / 2097152.0f);  // (1+beta)*mean
        out[OFF_PERP] = expf(-s);
    }
}

extern "C" void kernel_launch(void* const* d_in, const int* in_sizes, int n_in,
                              void* d_out, int out_size, void* d_ws, size_t ws_size,
                              hipStream_t stream) {
    const float* z   = (const float*)d_in[0];
    const float* emb = (const float*)d_in[1];
    float* out     = (float*)d_out;
    int*   hist    = (int*)d_ws;
    float* partial = (float*)((char*)d_ws + 4096);
    float* e2buf   = (float*)((char*)d_ws + 8192);

    hipMemsetAsync(hist, 0, 4096, stream);
    vq_e2<<<8, 128, 0, stream>>>(emb, e2buf);
    vq_scan<<<GRID_A, TPB_A, 0, stream>>>(z, emb, e2buf, out);
    vq_epi<<<GRID_B, TPB_B, 0, stream>>>(z, emb, hist, partial, out);
    vq_final<<<1, 1024, 0, stream>>>(hist, partial, out);
}